// Round 15
// baseline (194.147 us; speedup 1.0000x reference)
//
#include <hip/hip_runtime.h>
#include <cfloat>

typedef _Float16 f16;
typedef f16 f16x8 __attribute__((ext_vector_type(8)));
typedef float f32x4 __attribute__((ext_vector_type(4)));

#define NTOK (256 * 2048)   // 524288 tokens
#define DDIM 64
#define K 512
#define TPB 256
#define GRID_MAIN 4096      // 4096 blocks * 4 waves * 32 tokens = 128 tokens/block
#define THR 1.0e-3f         // flag threshold; >=10x worst-case |v - (d - sx)| (RN splits)

// primary ws layout (bytes):
//   [0,131072)        f16 pack: 128 chunks (ct*4+ds*2+split) x 64 lanes x 8
//   [131072,133120)   se[512]
//   [133120,149504)   bsum[4096]
#define WS_NEEDED 149504

// same binary tree as the in-place t[j]+=t[j+s] reduction, evaluated
// depth-first in 8-elem groups: <=12 live VGPRs instead of 64 (r14's t[64]
// spilled: +65MB WRITE_SIZE, one 64B chunk per thread).
__device__ __forceinline__ float sq_tree64(const float* __restrict__ x) {
    float g0, g1, g2, g3, g4, g5, g6, g7;
#define GRP(G, dst)                                                                      \
    do {                                                                                 \
        float p0 = __fmul_rn(x[8 * G + 0], x[8 * G + 0]);                                \
        float p1 = __fmul_rn(x[8 * G + 1], x[8 * G + 1]);                                \
        float p2 = __fmul_rn(x[8 * G + 2], x[8 * G + 2]);                                \
        float p3 = __fmul_rn(x[8 * G + 3], x[8 * G + 3]);                                \
        float p4 = __fmul_rn(x[8 * G + 4], x[8 * G + 4]);                                \
        float p5 = __fmul_rn(x[8 * G + 5], x[8 * G + 5]);                                \
        float p6 = __fmul_rn(x[8 * G + 6], x[8 * G + 6]);                                \
        float p7 = __fmul_rn(x[8 * G + 7], x[8 * G + 7]);                                \
        dst = __fadd_rn(__fadd_rn(__fadd_rn(p0, p1), __fadd_rn(p2, p3)),                 \
                        __fadd_rn(__fadd_rn(p4, p5), __fadd_rn(p6, p7)));                \
    } while (0)
    GRP(0, g0); GRP(1, g1); GRP(2, g2); GRP(3, g3);
    GRP(4, g4); GRP(5, g5); GRP(6, g6); GRP(7, g7);
#undef GRP
    return __fadd_rn(__fadd_rn(__fadd_rn(g0, g1), __fadd_rn(g2, g3)),
                     __fadd_rn(__fadd_rn(g4, g5), __fadd_rn(g6, g7)));
}

// ---------- prep: pack -2e (f16 hi/lo RN split) + per-code norms, one launch ----------
__global__ void vq_prep_kernel(const float* __restrict__ emb, f16* __restrict__ pack,
                               float* __restrict__ se) {
    const int b = blockIdx.x, l = threadIdx.x;
    if (b < 128) {
        const int split = b & 1;
        const int ds = (b >> 1) & 1;
        const int ct = b >> 2;
        const int code = ct * 16 + (l & 15);   // B col = lane&15
        const int dbase = ds * 32 + (l >> 4) * 8;
        const float* src = emb + (size_t)code * DDIM + dbase;
        f16x8 v;
#pragma unroll
        for (int j = 0; j < 8; ++j) {
            float t = -2.0f * src[j];
            f16 h = (f16)t;
            if (split == 0) v[j] = h;
            else            v[j] = (f16)((t - (float)h) * 2048.0f);
        }
        *(f16x8*)(pack + (size_t)b * 512 + (size_t)l * 8) = v;
    } else {
        // senorm: blocks 128..135, lane handles one code (same tree as always)
        const int k = (b - 128) * 64 + l;
        se[k] = sq_tree64(emb + (size_t)k * DDIM);
    }
}

// senorm-only kernel kept for the small-ws fallback path
__global__ void vq_senorm_kernel(const float* __restrict__ emb,
                                 float* __restrict__ se) {
    int k = threadIdx.x;
    se[k] = sq_tree64(emb + (size_t)k * DDIM);
}

// issue one wave's share of a super-chunk (8 KB) directly to LDS (linear dst).
#define STAGE3(buf, s)                                                                   \
    do {                                                                                 \
        const char* _g = (const char*)pack + (size_t)(s) * 8192 + (size_t)w * 1024 +     \
                         (size_t)l * 16;                                                 \
        char* _d = (char*)(&Bbuf[(buf)][0]) + (size_t)w * 1024 + (size_t)l * 16;         \
        __builtin_amdgcn_global_load_lds(                                                \
            (const __attribute__((address_space(1))) unsigned int*)_g,                   \
            (__attribute__((address_space(3))) unsigned int*)_d, 16, 0, 0);              \
        __builtin_amdgcn_global_load_lds(                                                \
            (const __attribute__((address_space(1))) unsigned int*)(_g + 4096),          \
            (__attribute__((address_space(3))) unsigned int*)(_d + 4096), 16, 0, 0);     \
    } while (0)

// ---------- main: MFMA v-scan, TRIPLE-buffered LDS B (counted vmcnt, never 0
// mid-loop), in-block exact rescore. launch_bounds (256,4): proven no-spill;
// round-8/10 lesson: tighter caps spill A-frags (GB-scale scratch traffic).
// NO sched_barrier(0): m141/r14 lesson - order-pinning defeats the compiler's
// schedule; the "memory" clobber on the waitcnt asm already orders ds_reads. ----------
__global__ __launch_bounds__(TPB, 4) void vq_main_kernel(
        const float* __restrict__ xg, const float* __restrict__ emb,
        const f16* __restrict__ pack, const float* __restrict__ se,
        float* __restrict__ out, float* __restrict__ bsum) {
    __shared__ f16x8 Bbuf[3][512];       // 24 KB: triple-buffered supers (2 ct each)
    __shared__ float se_lds[K];          // 2 KB (keeps se out of the vmcnt stream)
    __shared__ int   kw_lds[4][2][16];   // kmin | flag<<31
    __shared__ float dw_lds[4][2][16];
    __shared__ float lp_tok[128];
    __shared__ int   list_lds[128];
    __shared__ int   nflag_lds;

    const int tid = threadIdx.x;
    const int w  = tid >> 6;
    const int l  = tid & 63;
    const int lg = l >> 4;
    const int lc = l & 15;
    const size_t base = ((size_t)blockIdx.x * 4 + w) * 32;

    // ---- preload se to LDS ----
    se_lds[tid] = se[tid];
    se_lds[tid + 256] = se[tid + 256];

    // ---- load x, build A-fragments (RN-split hi + scaled lo), compute sx ----
    f16x8 Ah[2][2], Al[2][2];
    float sx[2];
#pragma unroll
    for (int i = 0; i < 2; ++i) {
        const float* xp = xg + (base + i * 16 + lc) * DDIM + lg * 8;
        float acc = 0.f;
#pragma unroll
        for (int ds = 0; ds < 2; ++ds) {
            float4 u0 = *(const float4*)(xp + ds * 32);
            float4 u1 = *(const float4*)(xp + ds * 32 + 4);
            float v[8] = {u0.x, u0.y, u0.z, u0.w, u1.x, u1.y, u1.z, u1.w};
            f16x8 h, lo;
#pragma unroll
            for (int j = 0; j < 8; ++j) {
                f16 hh = (f16)v[j];
                h[j]  = hh;
                lo[j] = (f16)((v[j] - (float)hh) * 2048.0f);
                acc = __fmaf_rn(v[j], v[j], acc);
            }
            Ah[i][ds] = h; Al[i][ds] = lo;
        }
        sx[i] = acc;
    }
#pragma unroll
    for (int i = 0; i < 2; ++i) {
        sx[i] += __shfl_xor(sx[i], 16, 64);
        sx[i] += __shfl_xor(sx[i], 32, 64);
    }

    float dmin[2][4], dsec[2][4];
    int   kmin[2][4];
#pragma unroll
    for (int i = 0; i < 2; ++i)
#pragma unroll
        for (int r = 0; r < 4; ++r) { dmin[i][r] = FLT_MAX; dsec[i][r] = FLT_MAX; kmin[i][r] = 0; }

    __syncthreads();   // se_lds visible; drains A-build loads once

    // ---- K scan: 16 supers of 2 ct, depth-2 prefetch, counted vmcnt ----
    const int rot = blockIdx.x & 15;
    STAGE3(0, rot);
    STAGE3(1, (1 + rot) & 15);

    for (int sp = 0; sp < 16; ++sp) {
        const int cur = sp % 3;
        const int s  = (sp + rot) & 15;

        // counted wait: only the oldest super's 2 loads must complete; the
        // next super's 2 stay in flight across the barrier (never drain to 0
        // mid-loop).
        if (sp < 15) asm volatile("s_waitcnt vmcnt(2)" ::: "memory");
        else         asm volatile("s_waitcnt vmcnt(0)" ::: "memory");
        __builtin_amdgcn_s_barrier();

        if (sp < 14) STAGE3((sp + 2) % 3, (sp + 2 + rot) & 15);

#pragma unroll
        for (int cl = 0; cl < 2; ++cl) {
            const int ct = s * 2 + cl;
            const int code = ct * 16 + lc;
            const float sek = se_lds[ct * 16 + lc];
            f16x8 Bh0 = Bbuf[cur][cl * 256 +   0 + l];
            f16x8 Bl0 = Bbuf[cur][cl * 256 +  64 + l];
            f16x8 Bh1 = Bbuf[cur][cl * 256 + 128 + l];
            f16x8 Bl1 = Bbuf[cur][cl * 256 + 192 + l];
#pragma unroll
            for (int i = 0; i < 2; ++i) {
                f32x4 am = {sek, sek, sek, sek};
                f32x4 ac = {0.f, 0.f, 0.f, 0.f};
                am = __builtin_amdgcn_mfma_f32_16x16x32_f16(Ah[i][0], Bh0, am, 0, 0, 0);
                am = __builtin_amdgcn_mfma_f32_16x16x32_f16(Ah[i][1], Bh1, am, 0, 0, 0);
                ac = __builtin_amdgcn_mfma_f32_16x16x32_f16(Al[i][0], Bh0, ac, 0, 0, 0);
                ac = __builtin_amdgcn_mfma_f32_16x16x32_f16(Al[i][1], Bh1, ac, 0, 0, 0);
                ac = __builtin_amdgcn_mfma_f32_16x16x32_f16(Ah[i][0], Bl0, ac, 0, 0, 0);
                ac = __builtin_amdgcn_mfma_f32_16x16x32_f16(Ah[i][1], Bl1, ac, 0, 0, 0);
#pragma unroll
                for (int r = 0; r < 4; ++r) {
                    float v = __fmaf_rn(ac[r], 4.8828125e-4f, am[r]);
                    bool lt = v < dmin[i][r];
                    dsec[i][r] = __builtin_amdgcn_fmed3f(v, dmin[i][r], dsec[i][r]);
                    dmin[i][r] = fminf(v, dmin[i][r]);
                    kmin[i][r] = lt ? code : kmin[i][r];
                }
            }
        }
    }

    // cross-lane top-2 merge over the 16 code columns
#pragma unroll
    for (int i = 0; i < 2; ++i)
#pragma unroll
        for (int r = 0; r < 4; ++r) {
#pragma unroll
            for (int off = 1; off <= 8; off <<= 1) {
                float dvm = __shfl_xor(dmin[i][r], off, 64);
                int   kvm = __shfl_xor(kmin[i][r], off, 64);
                float dvs = __shfl_xor(dsec[i][r], off, 64);
                bool take = dvm < dmin[i][r];
                float lose = take ? dmin[i][r] : dvm;
                if (take) { dmin[i][r] = dvm; kmin[i][r] = kvm; }
                dsec[i][r] = fminf(fminf(dsec[i][r], dvs), lose);
            }
        }

    if (tid == 0) nflag_lds = 0;
    if (lc == 0) {
#pragma unroll
        for (int i = 0; i < 2; ++i)
#pragma unroll
            for (int r = 0; r < 4; ++r) {
                int fl = (dsec[i][r] <= dmin[i][r] + THR) ? 1 : 0;
                kw_lds[w][i][lg * 4 + r] = kmin[i][r] | (fl << 31);
                dw_lds[w][i][lg * 4 + r] = dmin[i][r];
            }
    }
    __syncthreads();

    // ---- DENSE-LANE nontemporal epilogue (round-13 fix: consecutive lanes ->
    // consecutive 16B; lane-strided layout caused 2.4x HBM write amplification)
#pragma unroll
    for (int m = 0; m < 8; ++m) {
        const int row = m * 4 + (l >> 4);
        const int kwv = kw_lds[w][row >> 4][row & 15] & 0x7fffffff;
        f32x4 vsrc = ((const f32x4*)(emb + (size_t)kwv * DDIM))[lc];
        __builtin_nontemporal_store(vsrc, (f32x4*)(out + (base + row) * DDIM) + lc);
    }

    // v-based loss fill (flagged -> 0, rescore overwrites with exact value)
    if (l < 16) {
        int k0 = kw_lds[w][0][l], k1 = kw_lds[w][1][l];
        lp_tok[w * 32 + l]      = (k0 < 0) ? 0.f : __fadd_rn(sx[0], dw_lds[w][0][l]);
        lp_tok[w * 32 + 16 + l] = (k1 < 0) ? 0.f : __fadd_rn(sx[1], dw_lds[w][1][l]);
    }
    // flag list build (order nondeterministic; per-token results are not)
    if (tid < 128) {
        if (kw_lds[tid >> 5][(tid >> 4) & 1][tid & 15] < 0)
            list_lds[atomicAdd(&nflag_lds, 1)] = tid;
    }
    __syncthreads();

    // ---- in-block rescore: ONE WAVE per flagged token, bit-exact round-2 math ----
    const int nf = nflag_lds;
    float* xrow = (float*)&Bbuf[0][0] + w * DDIM;   // per-wave scratch (Bbuf free)
    for (int ii = w; ii < nf; ii += 4) {
        const int tloc = list_lds[ii];
        const size_t tok = (size_t)blockIdx.x * 128 + tloc;

        if (l < 16)
            ((float4*)xrow)[l] = ((const float4*)(xg + tok * DDIM))[l];
        asm volatile("s_waitcnt vmcnt(0) lgkmcnt(0)" ::: "memory");

        // identical binary tree, depth-first evaluation (no t[64] spill)
        const float sxr = sq_tree64(xrow);

        float dmn = FLT_MAX;
        int   kmn = K;
#pragma unroll
        for (int c = 0; c < 8; ++c) {
            const int k = c * 64 + l;
            const float* ek = emb + (size_t)k * DDIM;
            const float sek = se_lds[k];
            float a0 = 0.f, a1 = 0.f, a2 = 0.f, a3 = 0.f;
#pragma unroll
            for (int j = 0; j < DDIM; j += 4) {
                float4 e4 = *(const float4*)(ek + j);
                a0 = __fmaf_rn(xrow[j + 0], e4.x, a0);
                a1 = __fmaf_rn(xrow[j + 1], e4.y, a1);
                a2 = __fmaf_rn(xrow[j + 2], e4.z, a2);
                a3 = __fmaf_rn(xrow[j + 3], e4.w, a3);
            }
            float dot = __fadd_rn(__fadd_rn(a0, a1), __fadd_rn(a2, a3));
            float d = __fsub_rn(__fadd_rn(sxr, sek), __fmul_rn(2.0f, dot));
            if (d < dmn) { dmn = d; kmn = k; }   // ascending k per lane, strict <
        }
#pragma unroll
        for (int o = 1; o <= 32; o <<= 1) {
            float dv = __shfl_xor(dmn, o, 64);
            int   kv = __shfl_xor(kmn, o, 64);
            if (dv < dmn || (dv == dmn && kv < kmn)) { dmn = dv; kmn = kv; }
        }

        {
            const float4* esrc = (const float4*)(emb + (size_t)kmn * DDIM);
            if (l < 16)
                ((float4*)(out + tok * DDIM))[l] = esrc[l];
            float lp = 0.f;
#pragma unroll
            for (int q = 0; q < DDIM / 4; ++q) {
                float4 v = esrc[q];
                float d0 = __fsub_rn(v.x, xrow[4 * q + 0]); lp = __fmaf_rn(d0, d0, lp);
                float d1 = __fsub_rn(v.y, xrow[4 * q + 1]); lp = __fmaf_rn(d1, d1, lp);
                float d2 = __fsub_rn(v.z, xrow[4 * q + 2]); lp = __fmaf_rn(d2, d2, lp);
                float d3 = __fsub_rn(v.w, xrow[4 * q + 3]); lp = __fmaf_rn(d3, d3, lp);
            }
            if (l == 0) lp_tok[tloc] = lp;
        }
    }
    __syncthreads();

    // deterministic block reduction of lp_tok[128] (fixed index-ordered tree)
    if (tid < 128) {
        float lp = lp_tok[tid];
#pragma unroll
        for (int o = 32; o >= 1; o >>= 1) lp += __shfl_down(lp, o, 64);
        if (l == 0) dw_lds[0][0][w] = lp;
    }
    __syncthreads();
    if (tid == 0)
        bsum[blockIdx.x] = __fadd_rn(dw_lds[0][0][0], dw_lds[0][0][1]);
}

// ---------- fallback: proven round-2 main kernel ----------
__global__ __launch_bounds__(TPB) void vq_main_f32_kernel(
        const float* __restrict__ xg, const float* __restrict__ emb,
        const float* __restrict__ se, float* __restrict__ out,
        float* __restrict__ bsum) {
    __shared__ int   lds_kmin[TPB];
    __shared__ float lds_red[TPB / 64];
    const int tid = threadIdx.x;
    const size_t tok = (size_t)blockIdx.x * TPB + tid;
    float x[DDIM];
    {
        const float4* xg4 = (const float4*)(xg + tok * DDIM);
#pragma unroll
        for (int q = 0; q < DDIM / 4; ++q) {
            float4 v = xg4[q];
            x[4 * q + 0] = v.x; x[4 * q + 1] = v.y;
            x[4 * q + 2] = v.z; x[4 * q + 3] = v.w;
        }
    }
    const float sx = sq_tree64(x);
    float dmin = FLT_MAX; int kmin = 0;
    for (int k = 0; k < K; ++k) {
        const float* ek = emb + (size_t)k * DDIM;
        const float sek = se[k];
        float a0 = 0.f, a1 = 0.f, a2 = 0.f, a3 = 0.f;
#pragma unroll
        for (int j = 0; j < DDIM; j += 4) {
            a0 = __fmaf_rn(x[j + 0], ek[j + 0], a0);
            a1 = __fmaf_rn(x[j + 1], ek[j + 1], a1);
            a2 = __fmaf_rn(x[j + 2], ek[j + 2], a2);
            a3 = __fmaf_rn(x[j + 3], ek[j + 3], a3);
        }
        float dot = __fadd_rn(__fadd_rn(a0, a1), __fadd_rn(a2, a3));
        float d = __fsub_rn(__fadd_rn(sx, sek), __fmul_rn(2.0f, dot));
        if (d < dmin) { dmin = d; kmin = k; }
    }
    float lp = 0.f;
    {
        const float4* e4 = (const float4*)(emb + (size_t)kmin * DDIM);
#pragma unroll
        for (int q = 0; q < DDIM / 4; ++q) {
            float4 v = e4[q];
            float d0 = __fsub_rn(v.x, x[4 * q + 0]); lp = __fmaf_rn(d0, d0, lp);
            float d1 = __fsub_rn(v.y, x[4 * q + 1]); lp = __fmaf_rn(d1, d1, lp);
            float d2 = __fsub_rn(v.z, x[4 * q + 2]); lp = __fmaf_rn(d2, d2, lp);
            float d3 = __fsub_rn(v.w, x[4 * q + 3]); lp = __fmaf_rn(d3, d3, lp);
        }
    }
    lds_kmin[tid] = kmin;
#pragma unroll
    for (int off = 32; off >= 1; off >>= 1) lp += __shfl_down(lp, off, 64);
    if ((tid & 63) == 0) lds_red[tid >> 6] = lp;
    __syncthreads();
    if (tid == 0) {
        float s = lds_red[0];
#pragma unroll
        for (int w = 1; w < TPB / 64; ++w) s = __fadd_rn(s, lds_red[w]);
        bsum[blockIdx.x] = s;
    }
    {
        const float4* emb4 = (const float4*)emb;
        float4* out4 = (float4*)out + (size_t)blockIdx.x * (TPB * DDIM / 4);
#pragma unroll
        for (int it = 0; it < (TPB * DDIM / 4) / TPB; ++it) {
            int m = it * TPB + tid;
            int t = m >> 4, q = m & 15;
            out4[m] = emb4[(size_t)lds_kmin[t] * 16 + q];
        }
    }
}

// ---------- final deterministic loss reduction ----------
__global__ void vq_loss_kernel(const float* __restrict__ bsum, int nb1,
                               float* __restrict__ out_losses) {
    __shared__ float red[256];
    int tid = threadIdx.x;
    float s = 0.f;
    for (int i = tid; i < nb1; i += 256) s = __fadd_rn(s, bsum[i]);
    red[tid] = s;
    __syncthreads();
    for (int off = 128; off >= 1; off >>= 1) {
        if (tid < off) red[tid] = __fadd_rn(red[tid], red[tid + off]);
        __syncthreads();
    }
    if (tid == 0) {
        float mean = red[0] / (float)((long long)NTOK * DDIM);
        out_losses[0] = 0.25f * mean;  // commitment_loss
        out_losses[1] = mean;          // embedding_loss
    }
}

extern "C" void kernel_launch(void* const* d_in, const int* in_sizes, int n_in,
                              void* d_out, int out_size, void* d_ws, size_t ws_size,
                              hipStream_t stream) {
    const float* xg  = (const float*)d_in[0];
    const float* emb = (const float*)d_in[1];
    float* out = (float*)d_out;
    char* ws = (char*)d_ws;

    if (ws_size >= (size_t)WS_NEEDED) {
        f16*   pack = (f16*)ws;
        float* se   = (float*)(ws + 131072);
        float* bsum = (float*)(ws + 133120);

        vq_prep_kernel<<<136, 64, 0, stream>>>(emb, pack, se);
        vq_main_kernel<<<GRID_MAIN, TPB, 0, stream>>>(xg, emb, pack, se, out, bsum);
        vq_loss_kernel<<<1, 256, 0, stream>>>(bsum, GRID_MAIN, out + (size_t)NTOK * DDIM);
    } else {
        // fallback: proven round-2 path (needs ~10 KB of ws)
        float* se   = (float*)ws;
        float* bsum = se + K;
        vq_senorm_kernel<<<1, K, 0, stream>>>(emb, se);
        vq_main_f32_kernel<<<NTOK / TPB, TPB, 0, stream>>>(xg, emb, se, out, bsum);
        vq_loss_kernel<<<1, 256, 0, stream>>>(bsum, NTOK / TPB, out + (size_t)NTOK * DDIM);
    }
}

// Round 16
// 190.796 us; speedup vs baseline: 1.0176x; 1.0176x over previous
//
#include <hip/hip_runtime.h>
#include <cfloat>

typedef _Float16 f16;
typedef f16 f16x8 __attribute__((ext_vector_type(8)));
typedef float f32x4 __attribute__((ext_vector_type(4)));

#define NTOK (256 * 2048)   // 524288 tokens
#define DDIM 64
#define K 512
#define TPB 256
#define GRID_MAIN 4096      // 4096 blocks * 4 waves * 32 tokens
#define GRID_RES  2048      // rescore: 256 tokens/block
#define THR 1.0e-3f         // flag threshold; >=10x worst-case |v - (d - sx)| (RN splits)

// primary ws layout (bytes):
//   [0,131072)        f16 pack: 128 chunks (ct*4+ds*2+split) x 64 lanes x 8
//   [131072,133120)   se[512]
//   [133120,149504)   bsum[4096]
//   [149504,157696)   bsum2[2048]
//   [157696,681984)   flags[524288] bytes
#define WS_NEEDED 681984

// low-register binary tree (r15 fix kept): same association as the in-place
// t[j]+=t[j+s] tree, depth-first in 8-elem groups.
__device__ __forceinline__ float sq_tree64(const float* __restrict__ x) {
    float g0, g1, g2, g3, g4, g5, g6, g7;
#define GRP(G, dst)                                                                      \
    do {                                                                                 \
        float p0 = __fmul_rn(x[8 * G + 0], x[8 * G + 0]);                                \
        float p1 = __fmul_rn(x[8 * G + 1], x[8 * G + 1]);                                \
        float p2 = __fmul_rn(x[8 * G + 2], x[8 * G + 2]);                                \
        float p3 = __fmul_rn(x[8 * G + 3], x[8 * G + 3]);                                \
        float p4 = __fmul_rn(x[8 * G + 4], x[8 * G + 4]);                                \
        float p5 = __fmul_rn(x[8 * G + 5], x[8 * G + 5]);                                \
        float p6 = __fmul_rn(x[8 * G + 6], x[8 * G + 6]);                                \
        float p7 = __fmul_rn(x[8 * G + 7], x[8 * G + 7]);                                \
        dst = __fadd_rn(__fadd_rn(__fadd_rn(p0, p1), __fadd_rn(p2, p3)),                 \
                        __fadd_rn(__fadd_rn(p4, p5), __fadd_rn(p6, p7)));                \
    } while (0)
    GRP(0, g0); GRP(1, g1); GRP(2, g2); GRP(3, g3);
    GRP(4, g4); GRP(5, g5); GRP(6, g6); GRP(7, g7);
#undef GRP
    return __fadd_rn(__fadd_rn(__fadd_rn(g0, g1), __fadd_rn(g2, g3)),
                     __fadd_rn(__fadd_rn(g4, g5), __fadd_rn(g6, g7)));
}

// ---------- prep: pack -2e (f16 hi/lo RN split) + per-code norms, one launch ----------
__global__ void vq_prep_kernel(const float* __restrict__ emb, f16* __restrict__ pack,
                               float* __restrict__ se) {
    const int b = blockIdx.x, l = threadIdx.x;
    if (b < 128) {
        const int split = b & 1;
        const int ds = (b >> 1) & 1;
        const int ct = b >> 2;
        const int code = ct * 16 + (l & 15);   // B col = lane&15
        const int dbase = ds * 32 + (l >> 4) * 8;
        const float* src = emb + (size_t)code * DDIM + dbase;
        f16x8 v;
#pragma unroll
        for (int j = 0; j < 8; ++j) {
            float t = -2.0f * src[j];
            f16 h = (f16)t;
            if (split == 0) v[j] = h;
            else            v[j] = (f16)((t - (float)h) * 2048.0f);
        }
        *(f16x8*)(pack + (size_t)b * 512 + (size_t)l * 8) = v;
    } else {
        const int k = (b - 128) * 64 + l;      // blocks 128..135
        se[k] = sq_tree64(emb + (size_t)k * DDIM);
    }
}

// senorm-only kernel kept for the small-ws fallback path
__global__ void vq_senorm_kernel(const float* __restrict__ emb,
                                 float* __restrict__ se) {
    int k = threadIdx.x;
    se[k] = sq_tree64(emb + (size_t)k * DDIM);
}

// issue one wave's share (4 KB) of a 16 KB super-chunk (4 ct) to LDS (linear dst).
#define STAGE_SUPER(buf, s)                                                              \
    do {                                                                                 \
        const char* _g = (const char*)pack + (size_t)(s) * 16384 + (size_t)w * 4096 +    \
                         (size_t)l * 16;                                                 \
        char* _d = (char*)(&Bbuf[(buf)][0]) + (size_t)w * 4096 + (size_t)l * 16;         \
        __builtin_amdgcn_global_load_lds(                                                \
            (const __attribute__((address_space(1))) unsigned int*)_g,                   \
            (__attribute__((address_space(3))) unsigned int*)_d, 16, 0, 0);              \
        __builtin_amdgcn_global_load_lds(                                                \
            (const __attribute__((address_space(1))) unsigned int*)(_g + 1024),          \
            (__attribute__((address_space(3))) unsigned int*)(_d + 1024), 16, 0, 0);     \
        __builtin_amdgcn_global_load_lds(                                                \
            (const __attribute__((address_space(1))) unsigned int*)(_g + 2048),          \
            (__attribute__((address_space(3))) unsigned int*)(_d + 2048), 16, 0, 0);     \
        __builtin_amdgcn_global_load_lds(                                                \
            (const __attribute__((address_space(1))) unsigned int*)(_g + 3072),          \
            (__attribute__((address_space(3))) unsigned int*)(_d + 3072), 16, 0, 0);     \
    } while (0)

// ---------- main: MFMA v-scan, 8 supers of 4 ct (HALF the barriers of r13),
// double-buffered LDS B, named-reg se prefetch. launch_bounds (256,4): proven
// no-spill. Round-8/10 lesson: tighter caps spill A-frags (GB-scale scratch).
// Rescore stays a SEPARATE kernel: r14/15 showed fusing it degrades main
// (global regalloc -> residual scratch; main 163 -> 230). ----------
__global__ __launch_bounds__(TPB, 4) void vq_main_kernel(
        const float* __restrict__ xg, const float* __restrict__ emb,
        const f16* __restrict__ pack, const float* __restrict__ se,
        float* __restrict__ out, float* __restrict__ bsum,
        unsigned char* __restrict__ flags) {
    __shared__ f16x8 Bbuf[2][1024];      // 2 x 16 KB: double-buffered super (4 ct)
    __shared__ int   kw_lds[4][2][16];   // kmin | flag<<31
    __shared__ float dw_lds[4][2][16];
    __shared__ float wave_part[4];

    const int tid = threadIdx.x;
    const int w  = tid >> 6;
    const int l  = tid & 63;
    const int lg = l >> 4;
    const int lc = l & 15;
    const size_t base = ((size_t)blockIdx.x * 4 + w) * 32;

    // ---- load x, build A-fragments (RN-split hi + scaled lo), compute sx ----
    f16x8 Ah[2][2], Al[2][2];
    float sx[2];
#pragma unroll
    for (int i = 0; i < 2; ++i) {
        const float* xp = xg + (base + i * 16 + lc) * DDIM + lg * 8;
        float acc = 0.f;
#pragma unroll
        for (int ds = 0; ds < 2; ++ds) {
            float4 u0 = *(const float4*)(xp + ds * 32);
            float4 u1 = *(const float4*)(xp + ds * 32 + 4);
            float v[8] = {u0.x, u0.y, u0.z, u0.w, u1.x, u1.y, u1.z, u1.w};
            f16x8 h, lo;
#pragma unroll
            for (int j = 0; j < 8; ++j) {
                f16 hh = (f16)v[j];
                h[j]  = hh;
                lo[j] = (f16)((v[j] - (float)hh) * 2048.0f);
                acc = __fmaf_rn(v[j], v[j], acc);
            }
            Ah[i][ds] = h; Al[i][ds] = lo;
        }
        sx[i] = acc;
    }
#pragma unroll
    for (int i = 0; i < 2; ++i) {
        sx[i] += __shfl_xor(sx[i], 16, 64);
        sx[i] += __shfl_xor(sx[i], 32, 64);
    }

    float dmin[2][4], dsec[2][4];
    int   kmin[2][4];
#pragma unroll
    for (int i = 0; i < 2; ++i)
#pragma unroll
        for (int r = 0; r < 4; ++r) { dmin[i][r] = FLT_MAX; dsec[i][r] = FLT_MAX; kmin[i][r] = 0; }

    // ---- K scan: 8 supers of 4 code-tiles, double-buffered, rotated order ----
    const int rot = blockIdx.x & 7;
    const float* sebase = se + lc;
    float cs0 = sebase[rot * 64], cs1 = sebase[rot * 64 + 16],
          cs2 = sebase[rot * 64 + 32], cs3 = sebase[rot * 64 + 48];
    STAGE_SUPER(0, rot);                 // prologue

    for (int sp = 0; sp < 8; ++sp) {
        const int cur = sp & 1;
        const int s  = (sp + rot) & 7;   // super being computed this iteration

        // wait for THIS wave's loads of buf[cur] (issued last iter; latency
        // hidden under last iter's compute), then raw barrier.
        asm volatile("s_waitcnt vmcnt(0)" ::: "memory");
        __builtin_amdgcn_s_barrier();

        float ns0 = 0.f, ns1 = 0.f, ns2 = 0.f, ns3 = 0.f;
        if (sp < 7) {
            STAGE_SUPER(cur ^ 1, (sp + 1 + rot) & 7);    // prefetch next B super
            const int sn = ((sp + 1 + rot) & 7) * 64;    // prefetch next se
            ns0 = sebase[sn]; ns1 = sebase[sn + 16];
            ns2 = sebase[sn + 32]; ns3 = sebase[sn + 48];
        }

#pragma unroll
        for (int cl = 0; cl < 4; ++cl) {
            const int ct = s * 4 + cl;
            const int code = ct * 16 + lc;
            const float sek = (cl == 0) ? cs0 : (cl == 1) ? cs1 : (cl == 2) ? cs2 : cs3;
            f16x8 Bh0 = Bbuf[cur][cl * 256 +   0 + l];
            f16x8 Bl0 = Bbuf[cur][cl * 256 +  64 + l];
            f16x8 Bh1 = Bbuf[cur][cl * 256 + 128 + l];
            f16x8 Bl1 = Bbuf[cur][cl * 256 + 192 + l];
#pragma unroll
            for (int i = 0; i < 2; ++i) {
                f32x4 am = {sek, sek, sek, sek};
                f32x4 ac = {0.f, 0.f, 0.f, 0.f};
                am = __builtin_amdgcn_mfma_f32_16x16x32_f16(Ah[i][0], Bh0, am, 0, 0, 0);
                am = __builtin_amdgcn_mfma_f32_16x16x32_f16(Ah[i][1], Bh1, am, 0, 0, 0);
                ac = __builtin_amdgcn_mfma_f32_16x16x32_f16(Al[i][0], Bh0, ac, 0, 0, 0);
                ac = __builtin_amdgcn_mfma_f32_16x16x32_f16(Al[i][1], Bh1, ac, 0, 0, 0);
                ac = __builtin_amdgcn_mfma_f32_16x16x32_f16(Ah[i][0], Bl0, ac, 0, 0, 0);
                ac = __builtin_amdgcn_mfma_f32_16x16x32_f16(Ah[i][1], Bl1, ac, 0, 0, 0);
#pragma unroll
                for (int r = 0; r < 4; ++r) {
                    float v = __fmaf_rn(ac[r], 4.8828125e-4f, am[r]);
                    bool lt = v < dmin[i][r];
                    dsec[i][r] = __builtin_amdgcn_fmed3f(v, dmin[i][r], dsec[i][r]);
                    dmin[i][r] = fminf(v, dmin[i][r]);
                    kmin[i][r] = lt ? code : kmin[i][r];
                }
            }
        }
        cs0 = ns0; cs1 = ns1; cs2 = ns2; cs3 = ns3;
    }

    // cross-lane top-2 merge over the 16 code columns
#pragma unroll
    for (int i = 0; i < 2; ++i)
#pragma unroll
        for (int r = 0; r < 4; ++r) {
#pragma unroll
            for (int off = 1; off <= 8; off <<= 1) {
                float dvm = __shfl_xor(dmin[i][r], off, 64);
                int   kvm = __shfl_xor(kmin[i][r], off, 64);
                float dvs = __shfl_xor(dsec[i][r], off, 64);
                bool take = dvm < dmin[i][r];
                float lose = take ? dmin[i][r] : dvm;
                if (take) { dmin[i][r] = dvm; kmin[i][r] = kvm; }
                dsec[i][r] = fminf(fminf(dsec[i][r], dvs), lose);
            }
        }

    if (lc == 0) {
#pragma unroll
        for (int i = 0; i < 2; ++i)
#pragma unroll
            for (int r = 0; r < 4; ++r) {
                int fl = (dsec[i][r] <= dmin[i][r] + THR) ? 1 : 0;
                kw_lds[w][i][lg * 4 + r] = kmin[i][r] | (fl << 31);
                dw_lds[w][i][lg * 4 + r] = dmin[i][r];
                flags[base + i * 16 + lg * 4 + r] = (unsigned char)fl;
            }
    }
    __syncthreads();

    // ---- DENSE-LANE nontemporal epilogue (r13 fix: consecutive lanes ->
    // consecutive 16B; lane-strided layout caused 2.4x write amplification)
#pragma unroll
    for (int m = 0; m < 8; ++m) {
        const int row = m * 4 + (l >> 4);
        const int kwv = kw_lds[w][row >> 4][row & 15] & 0x7fffffff;
        f32x4 vsrc = ((const f32x4*)(emb + (size_t)kwv * DDIM))[lc];
        __builtin_nontemporal_store(vsrc, (f32x4*)(out + (base + row) * DDIM) + lc);
    }

    // loss partial (v-based); flagged tokens excluded (rescore supplies exact)
    float lp = 0.f;
    if (l < 16) {
        int k0 = kw_lds[w][0][l], k1 = kw_lds[w][1][l];
        float t0 = (k0 < 0) ? 0.f : __fadd_rn(sx[0], dw_lds[w][0][l]);
        float t1 = (k1 < 0) ? 0.f : __fadd_rn(sx[1], dw_lds[w][1][l]);
        lp = __fadd_rn(t0, t1);
    }
#pragma unroll
    for (int off = 32; off >= 1; off >>= 1) lp += __shfl_down(lp, off, 64);
    if (l == 0) wave_part[w] = lp;
    __syncthreads();
    if (tid == 0) {
        bsum[blockIdx.x] = __fadd_rn(__fadd_rn(wave_part[0], wave_part[1]),
                                     __fadd_rn(wave_part[2], wave_part[3]));
    }
}

// ---------- rescore flagged tokens: ONE WAVE per token, bit-exact round-2 math ----------
__global__ __launch_bounds__(TPB) void vq_rescore_kernel(
        const float* __restrict__ xg, const float* __restrict__ emb,
        const float* __restrict__ se, const unsigned char* __restrict__ flags,
        float* __restrict__ out, float* __restrict__ bsum2) {
    __shared__ int   list[TPB];
    __shared__ float lp_tok[TPB];
    __shared__ int   wcnt[4];
    __shared__ float x_lds[4][DDIM];
    __shared__ float red[TPB / 64];

    const int tid = threadIdx.x;
    const int w = tid >> 6, lane = tid & 63;
    const size_t tok0 = (size_t)blockIdx.x * TPB;
    const int flag = flags[tok0 + tid] != 0;

    lp_tok[tid] = 0.f;
    unsigned long long bal = __ballot(flag);
    if (lane == 0) wcnt[w] = __popcll(bal);
    __syncthreads();
    int off = 0;
#pragma unroll
    for (int ww = 0; ww < 4; ++ww) off += (ww < w) ? wcnt[ww] : 0;
    const int cnt = wcnt[0] + wcnt[1] + wcnt[2] + wcnt[3];
    if (flag) list[off + __popcll(bal & ((1ULL << lane) - 1))] = tid;
    __syncthreads();

    for (int i = w; i < cnt; i += 4) {
        const int tloc = __builtin_amdgcn_readfirstlane(list[i]);
        const size_t tok = tok0 + tloc;

        if (lane < 16)
            ((float4*)&x_lds[w][0])[lane] = ((const float4*)(xg + tok * DDIM))[lane];
        asm volatile("s_waitcnt vmcnt(0) lgkmcnt(0)" ::: "memory");

        const float sx = sq_tree64(&x_lds[w][0]);

        float dmin = FLT_MAX;
        int   kmin = K;
#pragma unroll
        for (int c = 0; c < 8; ++c) {
            const int k = c * 64 + lane;
            const float* ek = emb + (size_t)k * DDIM;
            const float sek = se[k];
            float a0 = 0.f, a1 = 0.f, a2 = 0.f, a3 = 0.f;
#pragma unroll
            for (int j = 0; j < DDIM; j += 4) {
                float4 e4 = *(const float4*)(ek + j);
                a0 = __fmaf_rn(x_lds[w][j + 0], e4.x, a0);
                a1 = __fmaf_rn(x_lds[w][j + 1], e4.y, a1);
                a2 = __fmaf_rn(x_lds[w][j + 2], e4.z, a2);
                a3 = __fmaf_rn(x_lds[w][j + 3], e4.w, a3);
            }
            float dot = __fadd_rn(__fadd_rn(a0, a1), __fadd_rn(a2, a3));
            float d = __fsub_rn(__fadd_rn(sx, sek), __fmul_rn(2.0f, dot));
            if (d < dmin) { dmin = d; kmin = k; }
        }
#pragma unroll
        for (int o = 1; o <= 32; o <<= 1) {
            float dv = __shfl_xor(dmin, o, 64);
            int   kv = __shfl_xor(kmin, o, 64);
            if (dv < dmin || (dv == dmin && kv < kmin)) { dmin = dv; kmin = kv; }
        }

        {
            const float4* esrc = (const float4*)(emb + (size_t)kmin * DDIM);
            if (lane < 16)
                ((float4*)(out + tok * DDIM))[lane] = esrc[lane];
            float lp = 0.f;
#pragma unroll
            for (int q = 0; q < DDIM / 4; ++q) {
                float4 v = esrc[q];
                float d0 = __fsub_rn(v.x, x_lds[w][4 * q + 0]); lp = __fmaf_rn(d0, d0, lp);
                float d1 = __fsub_rn(v.y, x_lds[w][4 * q + 1]); lp = __fmaf_rn(d1, d1, lp);
                float d2 = __fsub_rn(v.z, x_lds[w][4 * q + 2]); lp = __fmaf_rn(d2, d2, lp);
                float d3 = __fsub_rn(v.w, x_lds[w][4 * q + 3]); lp = __fmaf_rn(d3, d3, lp);
            }
            if (lane == 0) lp_tok[tloc] = lp;
        }
    }
    __syncthreads();

    float lp = lp_tok[tid];
#pragma unroll
    for (int o = 32; o >= 1; o >>= 1) lp += __shfl_down(lp, o, 64);
    if (lane == 0) red[w] = lp;
    __syncthreads();
    if (tid == 0) {
        bsum2[blockIdx.x] = __fadd_rn(__fadd_rn(red[0], red[1]),
                                      __fadd_rn(red[2], red[3]));
    }
}

// ---------- fallback: proven round-2 main kernel ----------
__global__ __launch_bounds__(TPB) void vq_main_f32_kernel(
        const float* __restrict__ xg, const float* __restrict__ emb,
        const float* __restrict__ se, float* __restrict__ out,
        float* __restrict__ bsum) {
    __shared__ int   lds_kmin[TPB];
    __shared__ float lds_red[TPB / 64];
    const int tid = threadIdx.x;
    const size_t tok = (size_t)blockIdx.x * TPB + tid;
    float x[DDIM];
    {
        const float4* xg4 = (const float4*)(xg + tok * DDIM);
#pragma unroll
        for (int q = 0; q < DDIM / 4; ++q) {
            float4 v = xg4[q];
            x[4 * q + 0] = v.x; x[4 * q + 1] = v.y;
            x[4 * q + 2] = v.z; x[4 * q + 3] = v.w;
        }
    }
    const float sx = sq_tree64(x);
    float dmin = FLT_MAX; int kmin = 0;
    for (int k = 0; k < K; ++k) {
        const float* ek = emb + (size_t)k * DDIM;
        const float sek = se[k];
        float a0 = 0.f, a1 = 0.f, a2 = 0.f, a3 = 0.f;
#pragma unroll
        for (int j = 0; j < DDIM; j += 4) {
            a0 = __fmaf_rn(x[j + 0], ek[j + 0], a0);
            a1 = __fmaf_rn(x[j + 1], ek[j + 1], a1);
            a2 = __fmaf_rn(x[j + 2], ek[j + 2], a2);
            a3 = __fmaf_rn(x[j + 3], ek[j + 3], a3);
        }
        float dot = __fadd_rn(__fadd_rn(a0, a1), __fadd_rn(a2, a3));
        float d = __fsub_rn(__fadd_rn(sx, sek), __fmul_rn(2.0f, dot));
        if (d < dmin) { dmin = d; kmin = k; }
    }
    float lp = 0.f;
    {
        const float4* e4 = (const float4*)(emb + (size_t)kmin * DDIM);
#pragma unroll
        for (int q = 0; q < DDIM / 4; ++q) {
            float4 v = e4[q];
            float d0 = __fsub_rn(v.x, x[4 * q + 0]); lp = __fmaf_rn(d0, d0, lp);
            float d1 = __fsub_rn(v.y, x[4 * q + 1]); lp = __fmaf_rn(d1, d1, lp);
            float d2 = __fsub_rn(v.z, x[4 * q + 2]); lp = __fmaf_rn(d2, d2, lp);
            float d3 = __fsub_rn(v.w, x[4 * q + 3]); lp = __fmaf_rn(d3, d3, lp);
        }
    }
    lds_kmin[tid] = kmin;
#pragma unroll
    for (int off = 32; off >= 1; off >>= 1) lp += __shfl_down(lp, off, 64);
    if ((tid & 63) == 0) lds_red[tid >> 6] = lp;
    __syncthreads();
    if (tid == 0) {
        float s = lds_red[0];
#pragma unroll
        for (int w = 1; w < TPB / 64; ++w) s = __fadd_rn(s, lds_red[w]);
        bsum[blockIdx.x] = s;
    }
    {
        const float4* emb4 = (const float4*)emb;
        float4* out4 = (float4*)out + (size_t)blockIdx.x * (TPB * DDIM / 4);
#pragma unroll
        for (int it = 0; it < (TPB * DDIM / 4) / TPB; ++it) {
            int m = it * TPB + tid;
            int t = m >> 4, q = m & 15;
            out4[m] = emb4[(size_t)lds_kmin[t] * 16 + q];
        }
    }
}

// ---------- final deterministic loss reduction ----------
__global__ void vq_loss_kernel(const float* __restrict__ bsum, int nb1,
                               const float* __restrict__ bsum2, int nb2,
                               float* __restrict__ out_losses) {
    __shared__ float red[256];
    int tid = threadIdx.x;
    float s = 0.f;
    for (int i = tid; i < nb1; i += 256) s = __fadd_rn(s, bsum[i]);
    for (int i = tid; i < nb2; i += 256) s = __fadd_rn(s, bsum2[i]);
    red[tid] = s;
    __syncthreads();
    for (int off = 128; off >= 1; off >>= 1) {
        if (tid < off) red[tid] = __fadd_rn(red[tid], red[tid + off]);
        __syncthreads();
    }
    if (tid == 0) {
        float mean = red[0] / (float)((long long)NTOK * DDIM);
        out_losses[0] = 0.25f * mean;  // commitment_loss
        out_losses[1] = mean;          // embedding_loss
    }
}

extern "C" void kernel_launch(void* const* d_in, const int* in_sizes, int n_in,
                              void* d_out, int out_size, void* d_ws, size_t ws_size,
                              hipStream_t stream) {
    const float* xg  = (const float*)d_in[0];
    const float* emb = (const float*)d_in[1];
    float* out = (float*)d_out;
    char* ws = (char*)d_ws;

    if (ws_size >= (size_t)WS_NEEDED) {
        f16*   pack  = (f16*)ws;
        float* se    = (float*)(ws + 131072);
        float* bsum  = (float*)(ws + 133120);
        float* bsum2 = (float*)(ws + 149504);
        unsigned char* flags = (unsigned char*)(ws + 157696);

        vq_prep_kernel<<<136, 64, 0, stream>>>(emb, pack, se);
        vq_main_kernel<<<GRID_MAIN, TPB, 0, stream>>>(xg, emb, pack, se, out, bsum, flags);
        vq_rescore_kernel<<<GRID_RES, TPB, 0, stream>>>(xg, emb, se, flags, out, bsum2);
        vq_loss_kernel<<<1, 256, 0, stream>>>(bsum, GRID_MAIN, bsum2, GRID_RES,
                                              out + (size_t)NTOK * DDIM);
    } else {
        // fallback: proven round-2 path (needs ~10 KB of ws)
        float* se   = (float*)ws;
        float* bsum = se + K;
        vq_senorm_kernel<<<1, K, 0, stream>>>(emb, se);
        vq_main_f32_kernel<<<NTOK / TPB, TPB, 0, stream>>>(xg, emb, se, out, bsum);
        vq_loss_kernel<<<1, 256, 0, stream>>>(bsum, NTOK / TPB, bsum, 0,
                                              out + (size_t)NTOK * DDIM);
    }
}

// Round 17
// 190.073 us; speedup vs baseline: 1.0214x; 1.0038x over previous
//
#include <hip/hip_runtime.h>
#include <cfloat>

typedef _Float16 f16;
typedef f16 f16x8 __attribute__((ext_vector_type(8)));
typedef float f32x4 __attribute__((ext_vector_type(4)));

#define NTOK (256 * 2048)   // 524288 tokens
#define DDIM 64
#define K 512
#define TPB 256
#define GRID_MAIN 4096      // 4096 blocks * 4 waves * 32 tokens
#define GRID_RES  2048      // rescore: 256 tokens/block
#define THR 1.0e-3f         // flag threshold; >=10x worst-case |v - (d - sx)| (RN splits)

// primary ws layout (bytes):
//   [0,131072)        f16 pack: 128 chunks (ct*4+ds*2+split) x 64 lanes x 8
//   [131072,133120)   se[512]
//   [133120,149504)   bsum[4096]
//   [149504,157696)   bsum2[2048]
//   [157696,681984)   flags[524288] bytes
#define WS_NEEDED 681984

// low-register binary tree (r15 fix kept): same association as the in-place
// t[j]+=t[j+s] tree, depth-first in 8-elem groups.
__device__ __forceinline__ float sq_tree64(const float* __restrict__ x) {
    float g0, g1, g2, g3, g4, g5, g6, g7;
#define GRP(G, dst)                                                                      \
    do {                                                                                 \
        float p0 = __fmul_rn(x[8 * G + 0], x[8 * G + 0]);                                \
        float p1 = __fmul_rn(x[8 * G + 1], x[8 * G + 1]);                                \
        float p2 = __fmul_rn(x[8 * G + 2], x[8 * G + 2]);                                \
        float p3 = __fmul_rn(x[8 * G + 3], x[8 * G + 3]);                                \
        float p4 = __fmul_rn(x[8 * G + 4], x[8 * G + 4]);                                \
        float p5 = __fmul_rn(x[8 * G + 5], x[8 * G + 5]);                                \
        float p6 = __fmul_rn(x[8 * G + 6], x[8 * G + 6]);                                \
        float p7 = __fmul_rn(x[8 * G + 7], x[8 * G + 7]);                                \
        dst = __fadd_rn(__fadd_rn(__fadd_rn(p0, p1), __fadd_rn(p2, p3)),                 \
                        __fadd_rn(__fadd_rn(p4, p5), __fadd_rn(p6, p7)));                \
    } while (0)
    GRP(0, g0); GRP(1, g1); GRP(2, g2); GRP(3, g3);
    GRP(4, g4); GRP(5, g5); GRP(6, g6); GRP(7, g7);
#undef GRP
    return __fadd_rn(__fadd_rn(__fadd_rn(g0, g1), __fadd_rn(g2, g3)),
                     __fadd_rn(__fadd_rn(g4, g5), __fadd_rn(g6, g7)));
}

// ---------- prep: pack -2e (f16 hi/lo RN split) + per-code norms, one launch ----------
__global__ void vq_prep_kernel(const float* __restrict__ emb, f16* __restrict__ pack,
                               float* __restrict__ se) {
    const int b = blockIdx.x, l = threadIdx.x;
    if (b < 128) {
        const int split = b & 1;
        const int ds = (b >> 1) & 1;
        const int ct = b >> 2;
        const int code = ct * 16 + (l & 15);   // B col = lane&15
        const int dbase = ds * 32 + (l >> 4) * 8;
        const float* src = emb + (size_t)code * DDIM + dbase;
        f16x8 v;
#pragma unroll
        for (int j = 0; j < 8; ++j) {
            float t = -2.0f * src[j];
            f16 h = (f16)t;
            if (split == 0) v[j] = h;
            else            v[j] = (f16)((t - (float)h) * 2048.0f);
        }
        *(f16x8*)(pack + (size_t)b * 512 + (size_t)l * 8) = v;
    } else {
        const int k = (b - 128) * 64 + l;      // blocks 128..135
        se[k] = sq_tree64(emb + (size_t)k * DDIM);
    }
}

// senorm-only kernel kept for the small-ws fallback path
__global__ void vq_senorm_kernel(const float* __restrict__ emb,
                                 float* __restrict__ se) {
    int k = threadIdx.x;
    se[k] = sq_tree64(emb + (size_t)k * DDIM);
}

// issue one wave's share (2 KB) of an 8 KB super-chunk (2 ct) to LDS (linear dst).
#define STAGE3(buf, s)                                                                   \
    do {                                                                                 \
        const char* _g = (const char*)pack + (size_t)(s) * 8192 + (size_t)w * 1024 +     \
                         (size_t)l * 16;                                                 \
        char* _d = (char*)(&Bbuf[(buf)][0]) + (size_t)w * 1024 + (size_t)l * 16;         \
        __builtin_amdgcn_global_load_lds(                                                \
            (const __attribute__((address_space(1))) unsigned int*)_g,                   \
            (__attribute__((address_space(3))) unsigned int*)_d, 16, 0, 0);              \
        __builtin_amdgcn_global_load_lds(                                                \
            (const __attribute__((address_space(1))) unsigned int*)(_g + 4096),          \
            (__attribute__((address_space(3))) unsigned int*)(_d + 4096), 16, 0, 0);     \
    } while (0)

// ---------- main: MFMA v-scan, TRIPLE-buffered 2-ct supers, counted vmcnt(2)
// (never 0 mid-loop -> loads stay in flight across barriers), se in LDS (keeps
// the vmcnt stream pure: exactly 2 stage-loads per phase). 27.7 KB LDS ->
// 5 blocks/CU (20 waves/CU). launch_bounds (256,4): proven no-spill; r8/r10
// lesson: tighter caps spill A-frags (GB-scale scratch). Rescore SEPARATE:
// r14/15 showed fusing degrades main. No sched_barrier (m141/r14). ----------
__global__ __launch_bounds__(TPB, 4) void vq_main_kernel(
        const float* __restrict__ xg, const float* __restrict__ emb,
        const f16* __restrict__ pack, const float* __restrict__ se,
        float* __restrict__ out, float* __restrict__ bsum,
        unsigned char* __restrict__ flags) {
    __shared__ f16x8 Bbuf[3][512];       // 24 KB: triple-buffered supers (2 ct each)
    __shared__ float se_lds[K];          // 2 KB
    __shared__ int   kw_lds[4][2][16];   // kmin | flag<<31
    __shared__ float dw_lds[4][2][16];
    __shared__ float wave_part[4];

    const int tid = threadIdx.x;
    const int w  = tid >> 6;
    const int l  = tid & 63;
    const int lg = l >> 4;
    const int lc = l & 15;
    const size_t base = ((size_t)blockIdx.x * 4 + w) * 32;

    // ---- preload se to LDS ----
    se_lds[tid] = se[tid];
    se_lds[tid + 256] = se[tid + 256];

    // ---- load x, build A-fragments (RN-split hi + scaled lo), compute sx ----
    f16x8 Ah[2][2], Al[2][2];
    float sx[2];
#pragma unroll
    for (int i = 0; i < 2; ++i) {
        const float* xp = xg + (base + i * 16 + lc) * DDIM + lg * 8;
        float acc = 0.f;
#pragma unroll
        for (int ds = 0; ds < 2; ++ds) {
            float4 u0 = *(const float4*)(xp + ds * 32);
            float4 u1 = *(const float4*)(xp + ds * 32 + 4);
            float v[8] = {u0.x, u0.y, u0.z, u0.w, u1.x, u1.y, u1.z, u1.w};
            f16x8 h, lo;
#pragma unroll
            for (int j = 0; j < 8; ++j) {
                f16 hh = (f16)v[j];
                h[j]  = hh;
                lo[j] = (f16)((v[j] - (float)hh) * 2048.0f);
                acc = __fmaf_rn(v[j], v[j], acc);
            }
            Ah[i][ds] = h; Al[i][ds] = lo;
        }
        sx[i] = acc;
    }
#pragma unroll
    for (int i = 0; i < 2; ++i) {
        sx[i] += __shfl_xor(sx[i], 16, 64);
        sx[i] += __shfl_xor(sx[i], 32, 64);
    }

    float dmin[2][4], dsec[2][4];
    int   kmin[2][4];
#pragma unroll
    for (int i = 0; i < 2; ++i)
#pragma unroll
        for (int r = 0; r < 4; ++r) { dmin[i][r] = FLT_MAX; dsec[i][r] = FLT_MAX; kmin[i][r] = 0; }

    __syncthreads();   // se_lds visible; drains A-build/se loads BEFORE staging starts

    // ---- K scan: 16 supers of 2 ct, depth-2 prefetch, counted vmcnt ----
    const int rot = blockIdx.x & 15;
    STAGE3(0, rot);
    STAGE3(1, (1 + rot) & 15);

    for (int sp = 0; sp < 16; ++sp) {
        const int cur = sp % 3;
        const int s  = (sp + rot) & 15;

        // counted wait: only the oldest super's 2 loads must be done; the next
        // super's 2 stay in flight across the barrier.
        if (sp < 15) asm volatile("s_waitcnt vmcnt(2)" ::: "memory");
        else         asm volatile("s_waitcnt vmcnt(0)" ::: "memory");
        __builtin_amdgcn_s_barrier();

        if (sp < 14) STAGE3((sp + 2) % 3, (sp + 2 + rot) & 15);

#pragma unroll
        for (int cl = 0; cl < 2; ++cl) {
            const int ct = s * 2 + cl;
            const int code = ct * 16 + lc;
            const float sek = se_lds[ct * 16 + lc];
            f16x8 Bh0 = Bbuf[cur][cl * 256 +   0 + l];
            f16x8 Bl0 = Bbuf[cur][cl * 256 +  64 + l];
            f16x8 Bh1 = Bbuf[cur][cl * 256 + 128 + l];
            f16x8 Bl1 = Bbuf[cur][cl * 256 + 192 + l];
#pragma unroll
            for (int i = 0; i < 2; ++i) {
                f32x4 am = {sek, sek, sek, sek};
                f32x4 ac = {0.f, 0.f, 0.f, 0.f};
                am = __builtin_amdgcn_mfma_f32_16x16x32_f16(Ah[i][0], Bh0, am, 0, 0, 0);
                am = __builtin_amdgcn_mfma_f32_16x16x32_f16(Ah[i][1], Bh1, am, 0, 0, 0);
                ac = __builtin_amdgcn_mfma_f32_16x16x32_f16(Al[i][0], Bh0, ac, 0, 0, 0);
                ac = __builtin_amdgcn_mfma_f32_16x16x32_f16(Al[i][1], Bh1, ac, 0, 0, 0);
                ac = __builtin_amdgcn_mfma_f32_16x16x32_f16(Ah[i][0], Bl0, ac, 0, 0, 0);
                ac = __builtin_amdgcn_mfma_f32_16x16x32_f16(Ah[i][1], Bl1, ac, 0, 0, 0);
#pragma unroll
                for (int r = 0; r < 4; ++r) {
                    float v = __fmaf_rn(ac[r], 4.8828125e-4f, am[r]);
                    bool lt = v < dmin[i][r];
                    dsec[i][r] = __builtin_amdgcn_fmed3f(v, dmin[i][r], dsec[i][r]);
                    dmin[i][r] = fminf(v, dmin[i][r]);
                    kmin[i][r] = lt ? code : kmin[i][r];
                }
            }
        }
    }

    // cross-lane top-2 merge over the 16 code columns
#pragma unroll
    for (int i = 0; i < 2; ++i)
#pragma unroll
        for (int r = 0; r < 4; ++r) {
#pragma unroll
            for (int off = 1; off <= 8; off <<= 1) {
                float dvm = __shfl_xor(dmin[i][r], off, 64);
                int   kvm = __shfl_xor(kmin[i][r], off, 64);
                float dvs = __shfl_xor(dsec[i][r], off, 64);
                bool take = dvm < dmin[i][r];
                float lose = take ? dmin[i][r] : dvm;
                if (take) { dmin[i][r] = dvm; kmin[i][r] = kvm; }
                dsec[i][r] = fminf(fminf(dsec[i][r], dvs), lose);
            }
        }

    if (lc == 0) {
#pragma unroll
        for (int i = 0; i < 2; ++i)
#pragma unroll
            for (int r = 0; r < 4; ++r) {
                int fl = (dsec[i][r] <= dmin[i][r] + THR) ? 1 : 0;
                kw_lds[w][i][lg * 4 + r] = kmin[i][r] | (fl << 31);
                dw_lds[w][i][lg * 4 + r] = dmin[i][r];
                flags[base + i * 16 + lg * 4 + r] = (unsigned char)fl;
            }
    }
    __syncthreads();

    // ---- DENSE-LANE nontemporal epilogue (r13 fix: consecutive lanes ->
    // consecutive 16B; lane-strided layout caused 2.4x write amplification)
#pragma unroll
    for (int m = 0; m < 8; ++m) {
        const int row = m * 4 + (l >> 4);
        const int kwv = kw_lds[w][row >> 4][row & 15] & 0x7fffffff;
        f32x4 vsrc = ((const f32x4*)(emb + (size_t)kwv * DDIM))[lc];
        __builtin_nontemporal_store(vsrc, (f32x4*)(out + (base + row) * DDIM) + lc);
    }

    // loss partial (v-based); flagged tokens excluded (rescore supplies exact)
    float lp = 0.f;
    if (l < 16) {
        int k0 = kw_lds[w][0][l], k1 = kw_lds[w][1][l];
        float t0 = (k0 < 0) ? 0.f : __fadd_rn(sx[0], dw_lds[w][0][l]);
        float t1 = (k1 < 0) ? 0.f : __fadd_rn(sx[1], dw_lds[w][1][l]);
        lp = __fadd_rn(t0, t1);
    }
#pragma unroll
    for (int off = 32; off >= 1; off >>= 1) lp += __shfl_down(lp, off, 64);
    if (l == 0) wave_part[w] = lp;
    __syncthreads();
    if (tid == 0) {
        bsum[blockIdx.x] = __fadd_rn(__fadd_rn(wave_part[0], wave_part[1]),
                                     __fadd_rn(wave_part[2], wave_part[3]));
    }
}

// ---------- rescore flagged tokens: ONE WAVE per token, bit-exact round-2 math ----------
__global__ __launch_bounds__(TPB) void vq_rescore_kernel(
        const float* __restrict__ xg, const float* __restrict__ emb,
        const float* __restrict__ se, const unsigned char* __restrict__ flags,
        float* __restrict__ out, float* __restrict__ bsum2) {
    __shared__ int   list[TPB];
    __shared__ float lp_tok[TPB];
    __shared__ int   wcnt[4];
    __shared__ float x_lds[4][DDIM];
    __shared__ float red[TPB / 64];

    const int tid = threadIdx.x;
    const int w = tid >> 6, lane = tid & 63;
    const size_t tok0 = (size_t)blockIdx.x * TPB;
    const int flag = flags[tok0 + tid] != 0;

    lp_tok[tid] = 0.f;
    unsigned long long bal = __ballot(flag);
    if (lane == 0) wcnt[w] = __popcll(bal);
    __syncthreads();
    int off = 0;
#pragma unroll
    for (int ww = 0; ww < 4; ++ww) off += (ww < w) ? wcnt[ww] : 0;
    const int cnt = wcnt[0] + wcnt[1] + wcnt[2] + wcnt[3];
    if (flag) list[off + __popcll(bal & ((1ULL << lane) - 1))] = tid;
    __syncthreads();

    for (int i = w; i < cnt; i += 4) {
        const int tloc = __builtin_amdgcn_readfirstlane(list[i]);
        const size_t tok = tok0 + tloc;

        if (lane < 16)
            ((float4*)&x_lds[w][0])[lane] = ((const float4*)(xg + tok * DDIM))[lane];
        asm volatile("s_waitcnt vmcnt(0) lgkmcnt(0)" ::: "memory");

        const float sx = sq_tree64(&x_lds[w][0]);

        float dmin = FLT_MAX;
        int   kmin = K;
#pragma unroll
        for (int c = 0; c < 8; ++c) {
            const int k = c * 64 + lane;
            const float* ek = emb + (size_t)k * DDIM;
            const float sek = se[k];
            float a0 = 0.f, a1 = 0.f, a2 = 0.f, a3 = 0.f;
#pragma unroll
            for (int j = 0; j < DDIM; j += 4) {
                float4 e4 = *(const float4*)(ek + j);
                a0 = __fmaf_rn(x_lds[w][j + 0], e4.x, a0);
                a1 = __fmaf_rn(x_lds[w][j + 1], e4.y, a1);
                a2 = __fmaf_rn(x_lds[w][j + 2], e4.z, a2);
                a3 = __fmaf_rn(x_lds[w][j + 3], e4.w, a3);
            }
            float dot = __fadd_rn(__fadd_rn(a0, a1), __fadd_rn(a2, a3));
            float d = __fsub_rn(__fadd_rn(sx, sek), __fmul_rn(2.0f, dot));
            if (d < dmin) { dmin = d; kmin = k; }
        }
#pragma unroll
        for (int o = 1; o <= 32; o <<= 1) {
            float dv = __shfl_xor(dmin, o, 64);
            int   kv = __shfl_xor(kmin, o, 64);
            if (dv < dmin || (dv == dmin && kv < kmin)) { dmin = dv; kmin = kv; }
        }

        {
            const float4* esrc = (const float4*)(emb + (size_t)kmin * DDIM);
            if (lane < 16)
                ((float4*)(out + tok * DDIM))[lane] = esrc[lane];
            float lp = 0.f;
#pragma unroll
            for (int q = 0; q < DDIM / 4; ++q) {
                float4 v = esrc[q];
                float d0 = __fsub_rn(v.x, x_lds[w][4 * q + 0]); lp = __fmaf_rn(d0, d0, lp);
                float d1 = __fsub_rn(v.y, x_lds[w][4 * q + 1]); lp = __fmaf_rn(d1, d1, lp);
                float d2 = __fsub_rn(v.z, x_lds[w][4 * q + 2]); lp = __fmaf_rn(d2, d2, lp);
                float d3 = __fsub_rn(v.w, x_lds[w][4 * q + 3]); lp = __fmaf_rn(d3, d3, lp);
            }
            if (lane == 0) lp_tok[tloc] = lp;
        }
    }
    __syncthreads();

    float lp = lp_tok[tid];
#pragma unroll
    for (int o = 32; o >= 1; o >>= 1) lp += __shfl_down(lp, o, 64);
    if (lane == 0) red[w] = lp;
    __syncthreads();
    if (tid == 0) {
        bsum2[blockIdx.x] = __fadd_rn(__fadd_rn(red[0], red[1]),
                                      __fadd_rn(red[2], red[3]));
    }
}

// ---------- fallback: proven round-2 main kernel ----------
__global__ __launch_bounds__(TPB) void vq_main_f32_kernel(
        const float* __restrict__ xg, const float* __restrict__ emb,
        const float* __restrict__ se, float* __restrict__ out,
        float* __restrict__ bsum) {
    __shared__ int   lds_kmin[TPB];
    __shared__ float lds_red[TPB / 64];
    const int tid = threadIdx.x;
    const size_t tok = (size_t)blockIdx.x * TPB + tid;
    float x[DDIM];
    {
        const float4* xg4 = (const float4*)(xg + tok * DDIM);
#pragma unroll
        for (int q = 0; q < DDIM / 4; ++q) {
            float4 v = xg4[q];
            x[4 * q + 0] = v.x; x[4 * q + 1] = v.y;
            x[4 * q + 2] = v.z; x[4 * q + 3] = v.w;
        }
    }
    const float sx = sq_tree64(x);
    float dmin = FLT_MAX; int kmin = 0;
    for (int k = 0; k < K; ++k) {
        const float* ek = emb + (size_t)k * DDIM;
        const float sek = se[k];
        float a0 = 0.f, a1 = 0.f, a2 = 0.f, a3 = 0.f;
#pragma unroll
        for (int j = 0; j < DDIM; j += 4) {
            a0 = __fmaf_rn(x[j + 0], ek[j + 0], a0);
            a1 = __fmaf_rn(x[j + 1], ek[j + 1], a1);
            a2 = __fmaf_rn(x[j + 2], ek[j + 2], a2);
            a3 = __fmaf_rn(x[j + 3], ek[j + 3], a3);
        }
        float dot = __fadd_rn(__fadd_rn(a0, a1), __fadd_rn(a2, a3));
        float d = __fsub_rn(__fadd_rn(sx, sek), __fmul_rn(2.0f, dot));
        if (d < dmin) { dmin = d; kmin = k; }
    }
    float lp = 0.f;
    {
        const float4* e4 = (const float4*)(emb + (size_t)kmin * DDIM);
#pragma unroll
        for (int q = 0; q < DDIM / 4; ++q) {
            float4 v = e4[q];
            float d0 = __fsub_rn(v.x, x[4 * q + 0]); lp = __fmaf_rn(d0, d0, lp);
            float d1 = __fsub_rn(v.y, x[4 * q + 1]); lp = __fmaf_rn(d1, d1, lp);
            float d2 = __fsub_rn(v.z, x[4 * q + 2]); lp = __fmaf_rn(d2, d2, lp);
            float d3 = __fsub_rn(v.w, x[4 * q + 3]); lp = __fmaf_rn(d3, d3, lp);
        }
    }
    lds_kmin[tid] = kmin;
#pragma unroll
    for (int off = 32; off >= 1; off >>= 1) lp += __shfl_down(lp, off, 64);
    if ((tid & 63) == 0) lds_red[tid >> 6] = lp;
    __syncthreads();
    if (tid == 0) {
        float s = lds_red[0];
#pragma unroll
        for (int w = 1; w < TPB / 64; ++w) s = __fadd_rn(s, lds_red[w]);
        bsum[blockIdx.x] = s;
    }
    {
        const float4* emb4 = (const float4*)emb;
        float4* out4 = (float4*)out + (size_t)blockIdx.x * (TPB * DDIM / 4);
#pragma unroll
        for (int it = 0; it < (TPB * DDIM / 4) / TPB; ++it) {
            int m = it * TPB + tid;
            int t = m >> 4, q = m & 15;
            out4[m] = emb4[(size_t)lds_kmin[t] * 16 + q];
        }
    }
}

// ---------- final deterministic loss reduction ----------
__global__ void vq_loss_kernel(const float* __restrict__ bsum, int nb1,
                               const float* __restrict__ bsum2, int nb2,
                               float* __restrict__ out_losses) {
    __shared__ float red[256];
    int tid = threadIdx.x;
    float s = 0.f;
    for (int i = tid; i < nb1; i += 256) s = __fadd_rn(s, bsum[i]);
    for (int i = tid; i < nb2; i += 256) s = __fadd_rn(s, bsum2[i]);
    red[tid] = s;
    __syncthreads();
    for (int off = 128; off >= 1; off >>= 1) {
        if (tid < off) red[tid] = __fadd_rn(red[tid], red[tid + off]);
        __syncthreads();
    }
    if (tid == 0) {
        float mean = red[0] / (float)((long long)NTOK * DDIM);
        out_losses[0] = 0.25f * mean;  // commitment_loss
        out_losses[1] = mean;          // embedding_loss
    }
}

extern "C" void kernel_launch(void* const* d_in, const int* in_sizes, int n_in,
                              void* d_out, int out_size, void* d_ws, size_t ws_size,
                              hipStream_t stream) {
    const float* xg  = (const float*)d_in[0];
    const float* emb = (const float*)d_in[1];
    float* out = (float*)d_out;
    char* ws = (char*)d_ws;

    if (ws_size >= (size_t)WS_NEEDED) {
        f16*   pack  = (f16*)ws;
        float* se    = (float*)(ws + 131072);
        float* bsum  = (float*)(ws + 133120);
        float* bsum2 = (float*)(ws + 149504);
        unsigned char* flags = (unsigned char*)(ws + 157696);

        vq_prep_kernel<<<136, 64, 0, stream>>>(emb, pack, se);
        vq_main_kernel<<<GRID_MAIN, TPB, 0, stream>>>(xg, emb, pack, se, out, bsum, flags);
        vq_rescore_kernel<<<GRID_RES, TPB, 0, stream>>>(xg, emb, se, flags, out, bsum2);
        vq_loss_kernel<<<1, 256, 0, stream>>>(bsum, GRID_MAIN, bsum2, GRID_RES,
                                              out + (size_t)NTOK * DDIM);
    } else {
        // fallback: proven round-2 path (needs ~10 KB of ws)
        float* se   = (float*)ws;
        float* bsum = se + K;
        vq_senorm_kernel<<<1, K, 0, stream>>>(emb, se);
        vq_main_f32_kernel<<<NTOK / TPB, TPB, 0, stream>>>(xg, emb, se, out, bsum);
        vq_loss_kernel<<<1, 256, 0, stream>>>(bsum, NTOK / TPB, bsum, 0,
                                              out + (size_t)NTOK * DDIM);
    }
}